// Round 7
// baseline (177.829 us; speedup 1.0000x reference)
//
#include <hip/hip_runtime.h>
#include <hip/hip_bf16.h>
#include <stdint.h>

#define B_ 8
#define C_ 512
#define T_ 4096
#define O_ 512
#define KP_ 1728   /* padded K: 3 groups x 3 k x 192 */
#define EPS_ 1e-8f

#define BM 256
#define BN 128
#define FTP_ROWS 4104

typedef unsigned short ushort_t;
typedef __attribute__((ext_vector_type(4))) float f32x4;
typedef __attribute__((ext_vector_type(8))) short bf16x8;

__device__ __forceinline__ ushort_t f2bf(float f) {
  union { float f; uint32_t u; } x; x.f = f;
  uint32_t u = x.u;
  uint32_t r = (u + 0x7FFFu + ((u >> 16) & 1u)) >> 16;
  return (ushort_t)r;
}

#define GLOAD16(gsrc, ldst) \
  __builtin_amdgcn_global_load_lds((const __attribute__((address_space(1))) unsigned int*)(gsrc), \
                                   (__attribute__((address_space(3))) unsigned int*)(ldst), 16, 0, 0)

// ---------------- sim reduction: nn[t] = sum_c e^2, dl[t] = sum_c e[t]*e[t-1] ---------
__global__ void sim_reduce_kernel(const float* __restrict__ emb,
                                  float* __restrict__ nn_out,
                                  float* __restrict__ dl_out) {
  const int b = blockIdx.y;
  const int t0 = (blockIdx.x * 64 + threadIdx.x) * 4;
  const int cty = threadIdx.y;
  float nn0=0.f,nn1=0.f,nn2=0.f,nn3=0.f;
  float dl0=0.f,dl1=0.f,dl2=0.f,dl3=0.f;
  const float* base = emb + (size_t)b * C_ * T_;
  for (int c = cty * 128; c < cty * 128 + 128; ++c) {
    const float* row = base + (size_t)c * T_;
    float4 v = *(const float4*)(row + t0);
    float el = (t0 > 0) ? row[t0 - 1] : 0.f;
    nn0 += v.x*v.x; nn1 += v.y*v.y; nn2 += v.z*v.z; nn3 += v.w*v.w;
    dl0 += v.x*el;  dl1 += v.y*v.x; dl2 += v.z*v.y; dl3 += v.w*v.z;
  }
  __shared__ float red[4][64*8];
  float* myr = &red[cty][threadIdx.x * 8];
  if (cty != 0) {
    myr[0]=nn0; myr[1]=nn1; myr[2]=nn2; myr[3]=nn3;
    myr[4]=dl0; myr[5]=dl1; myr[6]=dl2; myr[7]=dl3;
  }
  __syncthreads();
  if (cty == 0) {
    for (int q = 1; q < 4; ++q) {
      float* r = &red[q][threadIdx.x * 8];
      nn0+=r[0]; nn1+=r[1]; nn2+=r[2]; nn3+=r[3];
      dl0+=r[4]; dl1+=r[5]; dl2+=r[6]; dl3+=r[7];
    }
    float* nb = nn_out + (size_t)b * T_ + t0;
    float* db = dl_out + (size_t)b * T_ + t0;
    nb[0]=nn0; nb[1]=nn1; nb[2]=nn2; nb[3]=nn3;
    db[0]=dl0; db[1]=dl1; db[2]=dl2; db[3]=dl3;
  }
}

// ---------------- fused: sim finalize (blocks 0..127) + weight permute (rest) --------
__global__ void prep_small_kernel(const float* __restrict__ nn,
                                  const float* __restrict__ dl,
                                  float* __restrict__ sim,
                                  const float* __restrict__ w,
                                  ushort_t* __restrict__ wbf) {
  const int bid = blockIdx.x;
  if (bid < 128) {
    const int idx = bid * 256 + threadIdx.x;
    const int b = idx >> 12;
    const int t = idx & (T_ - 1);
    const float* nnb = nn + (size_t)b * T_;
    const float* dlb = dl + (size_t)b * T_;
    float nncur = nnb[t];
    float ncur = fmaxf(sqrtf(nncur), EPS_);
    float sc = nncur / (ncur * ncur);
    float sl = 0.f, sr = 0.f;
    if (t > 0) {
      float np = fmaxf(sqrtf(nnb[t - 1]), EPS_);
      sl = dlb[t] / (ncur * np);
    }
    if (t < T_ - 1) {
      float nx = fmaxf(sqrtf(nnb[t + 1]), EPS_);
      sr = dlb[t + 1] / (ncur * nx);
    }
    float* simb = sim + (size_t)b * 3 * T_;
    simb[t] = sl;
    simb[T_ + t] = sc;
    simb[2 * T_ + t] = sr;
  } else {
    const int idx = (bid - 128) * 256 + threadIdx.x;
    if (idx >= O_ * KP_) return;
    const int o = idx / KP_;
    const int p = idx - o * KP_;
    const int g = p / 576; const int r = p - g * 576;
    const int k = r / 192; const int j = r - k * 192;
    const int c_lo = (512 * g - k + 2) / 3;
    const int c_hi = (512 * g + 511 - k) / 3;
    const int c = (c_lo & ~7) + j;
    float v = (c >= c_lo && c <= c_hi) ? w[((size_t)o * C_ + c) * 3 + k] : 0.f;
    wbf[idx] = f2bf(v);
  }
}

// ---------------- feature transpose+convert (+ zero pad rows when x==64) -------------
__global__ void transpose_kernel(const float* __restrict__ feat, ushort_t* __restrict__ Ftp) {
  const int b = blockIdx.z;
  const int c0 = blockIdx.y * 64;
  const int tid = threadIdx.x;
  if (blockIdx.x == T_ / 64) {  // pad rows t=-1 (row 0) and t=T (row 4097)
    if (tid < 64)        Ftp[((size_t)b * FTP_ROWS + 0) * 512 + c0 + tid] = 0;
    else if (tid < 128)  Ftp[((size_t)b * FTP_ROWS + T_ + 1) * 512 + c0 + (tid - 64)] = 0;
    return;
  }
  const int t0 = blockIdx.x * 64;
  __shared__ ushort_t LT[64 * 72];
  {
    const int cl = tid >> 2;
    const int tq = (tid & 3) * 16;
    const float* src = feat + ((size_t)b * C_ + c0 + cl) * T_ + t0 + tq;
    for (int q = 0; q < 4; ++q) {
      float4 v = *(const float4*)(src + q * 4);
      const int t = tq + q * 4;
      LT[(t + 0) * 72 + cl] = f2bf(v.x);
      LT[(t + 1) * 72 + cl] = f2bf(v.y);
      LT[(t + 2) * 72 + cl] = f2bf(v.z);
      LT[(t + 3) * 72 + cl] = f2bf(v.w);
    }
  }
  __syncthreads();
  {
    const int tl = tid >> 2;
    const int cq = (tid & 3) * 16;
    ushort_t* dst = Ftp + ((size_t)b * FTP_ROWS + t0 + tl + 1) * 512 + c0 + cq;
    *(uint4*)(dst) = *(const uint4*)&LT[tl * 72 + cq];
    *(uint4*)(dst + 8) = *(const uint4*)&LT[tl * 72 + cq + 8];
  }
}

// ------- main GEMM: 256x128, A global->reg (A-before-B issue order), B 4-ring LDS ----
__global__ __launch_bounds__(512, 2)
void conv_gemm_kernel(const ushort_t* __restrict__ Ftp,
                      const ushort_t* __restrict__ wbf,
                      const float* __restrict__ sim,
                      float* __restrict__ out) {
  __shared__ __align__(16) ushort_t lds[4 * 4096];  // 4-ring of B half-slabs (8 KB each)

  const int b = blockIdx.z;
  const int oBase = blockIdx.y * BM;
  const int tBase = blockIdx.x * BN;

  const int tid = threadIdx.x;
  const int lane = tid & 63;
  const int wid = tid >> 6;           // 8 waves
  const int wm = wid >> 1;            // 0..3 (o)
  const int wn = wid & 1;             // 0..1 (t)
  const int llo = lane & 15, lhi = lane >> 4;

  // B ds_read chunk swizzle + matching staging source swizzle (verified pair)
  const int rdsw = ((lhi ^ ((llo >> 1) & 3)) << 3);
  const int gch = ((lane & 3) ^ ((lane >> 3) & 3)) << 3;

  const ushort_t* ftpB = Ftp + (size_t)b * FTP_ROWS * 512;
  const float* simB = sim + (size_t)b * 3 * T_;

  // A fragment global bases (per m); per-phase k advance = u*32 ushorts
  const ushort_t* aB0 = wbf + (size_t)(oBase + wm * 64 + llo) * KP_ + lhi * 8;
  const ushort_t* aB[4] = {aB0, aB0 + 16 * KP_, aB0 + 32 * KP_, aB0 + 48 * KP_};

  // B staging source base: per-lane row (tBase + wid*16 + lane>>2), swizzled chunk
  const ushort_t* bRow = ftpB + (size_t)(tBase + wid * 16 + (lane >> 2)) * 512 + gch;

  // ---- preload sim, pin, drain ----
  float sv[3][4];
#pragma unroll
  for (int g = 0; g < 3; ++g)
#pragma unroll
    for (int n = 0; n < 4; ++n) {
      sv[g][n] = simB[g * T_ + tBase + wn * 64 + n * 16 + llo];
      asm volatile("" : "+v"(sv[g][n]));
    }
  asm volatile("s_waitcnt vmcnt(0)" ::: "memory");

  f32x4 cacc[4][4], oacc[4][4];
  const f32x4 vzero = {0.f, 0.f, 0.f, 0.f};
#pragma unroll
  for (int m = 0; m < 4; ++m)
#pragma unroll
    for (int n = 0; n < 4; ++n) { cacc[m][n] = vzero; oacc[m][n] = vzero; }

  // ---- stage B half-slab v into ring[v&3]: ONE gload_lds per wave ----
  auto GLOADB = [&](int v) {
    const int s2 = v >> 1, h = v & 1;
    const int g = s2 / 9, r = s2 - g * 9, k = r / 3, jb = r - k * 3;
    const int c_st = ((512 * g - k + 2) / 3) & ~7;
    GLOAD16(bRow + k * 512 + c_st + jb * 64 + h * 32, lds + (v & 3) * 4096 + wid * 512);
  };

  bf16x8 af[2][4];

  // ---- prologue: B(0), A(0), B(1), B(2) in flight; force B(0) landed ----
  GLOADB(0);
  __builtin_amdgcn_sched_barrier(0);
#pragma unroll
  for (int m = 0; m < 4; ++m)
    af[0][m] = *(const bf16x8*)(aB[m]);
  __builtin_amdgcn_sched_barrier(0);
  GLOADB(1); GLOADB(2);
  __builtin_amdgcn_sched_barrier(0);
  asm volatile("s_waitcnt vmcnt(6)" ::: "memory");   // B(0) landed (A0x4+B1+B2 remain)

#pragma unroll
  for (int u = 0; u < 54; ++u) {
    // barrier: all waves' B(u) landed (forced by their pre-barrier vmcnt waits),
    // all previous readers of slot (u+3)&3 drained (lgkmcnt(0) below).
    __builtin_amdgcn_s_barrier();
    __builtin_amdgcn_sched_barrier(0);

    // A(u+1) global->reg FIRST (so MFMA's wait on A(u) leaves B prefetches in flight)
    if (u + 1 < 54) {
#pragma unroll
      for (int m = 0; m < 4; ++m)
        af[(u + 1) & 1][m] = *(const bf16x8*)(aB[m] + (u + 1) * 32);
    }
    __builtin_amdgcn_sched_barrier(0);

    if (u + 3 < 54) GLOADB(u + 3);      // slot (u-1)&3: read-drained before this barrier
    __builtin_amdgcn_sched_barrier(0);

    // B fragments from LDS (compiler inserts lgkm waits before MFMA use)
    const ushort_t* Bs = lds + (u & 3) * 4096;
    bf16x8 bfv[4];
#pragma unroll
    for (int n = 0; n < 4; ++n)
      bfv[n] = *(const bf16x8*)&Bs[(wn * 64 + n * 16 + llo) * 32 + rdsw];

    // MFMA: compiler waits vmcnt for af[u&1] (issued phase u-1, before B(u+2)) ->
    // in-order force = {A(u), B(u+1) and older}; B(u+2), A(u+1), B(u+3) stay in flight.
    __builtin_amdgcn_s_setprio(1);
#pragma unroll
    for (int m = 0; m < 4; ++m)
#pragma unroll
      for (int n = 0; n < 4; ++n)
        cacc[m][n] = __builtin_amdgcn_mfma_f32_16x16x32_bf16(af[u & 1][m], bfv[n], cacc[m][n], 0, 0, 0);
    __builtin_amdgcn_s_setprio(0);

    asm volatile("s_waitcnt lgkmcnt(0)" ::: "memory");  // my ds_reads retired (WAR guard)
    __builtin_amdgcn_sched_barrier(0);

    // group boundary: fold sim_g * partial into output accumulator
    if (u == 17 || u == 35 || u == 53) {
      const int g = u / 18;
#pragma unroll
      for (int n = 0; n < 4; ++n) {
        const float sc = sv[g][n];
#pragma unroll
        for (int m = 0; m < 4; ++m) {
          oacc[m][n] += sc * cacc[m][n];
          cacc[m][n] = vzero;
        }
      }
    }
  }

  // ---- epilogue: D layout col=lane&15, row=(lane>>4)*4+reg ----
  float* outB = out + ((size_t)b * O_ + oBase) * T_ + tBase;
#pragma unroll
  for (int m = 0; m < 4; ++m) {
    const int r0 = wm * 64 + m * 16 + lhi * 4;
#pragma unroll
    for (int n = 0; n < 4; ++n) {
      const int cg = wn * 64 + n * 16 + llo;
#pragma unroll
      for (int r = 0; r < 4; ++r)
        outB[(size_t)(r0 + r) * T_ + cg] = oacc[m][n][r];
    }
  }
}

extern "C" void kernel_launch(void* const* d_in, const int* in_sizes, int n_in,
                              void* d_out, int out_size, void* d_ws, size_t ws_size,
                              hipStream_t stream) {
  const float* feature   = (const float*)d_in[0];
  const float* embedding = (const float*)d_in[1];
  const float* weight    = (const float*)d_in[2];
  float* out = (float*)d_out;

  float* ws  = (float*)d_ws;
  float* nn  = ws;                                   // B*T f32
  float* dl  = nn + (size_t)B_ * T_;                 // B*T f32
  float* sim = dl + (size_t)B_ * T_;                 // B*3*T f32
  ushort_t* wbf = (ushort_t*)(sim + (size_t)3 * B_ * T_);   // O*KP bf16
  ushort_t* Ftp = wbf + (size_t)O_ * KP_;                   // B*FTP_ROWS*C bf16

  sim_reduce_kernel<<<dim3(T_ / 256, B_), dim3(64, 4), 0, stream>>>(embedding, nn, dl);
  prep_small_kernel<<<dim3(128 + (O_ * KP_ + 255) / 256), 256, 0, stream>>>(nn, dl, sim, weight, wbf);
  transpose_kernel<<<dim3(T_ / 64 + 1, C_ / 64, B_), 256, 0, stream>>>(feature, Ftp);
  conv_gemm_kernel<<<dim3(T_ / BN, O_ / BM, B_), 512, 0, stream>>>(Ftp, wbf, sim, out);
}

// Round 8
// 117.909 us; speedup vs baseline: 1.5082x; 1.5082x over previous
//
#include <hip/hip_runtime.h>
#include <hip/hip_bf16.h>
#include <stdint.h>

#define B_ 8
#define C_ 512
#define T_ 4096
#define O_ 512
#define KP_ 1728   /* padded K: 3 groups x 3 k x 192 */
#define EPS_ 1e-8f

#define BM 256
#define BN 128
#define FTP_ROWS 4104

/* LDS ring: 4 half-slab buffers, each [A 256x32 = 8192 ush][B 128x32 = 4096 ush] */
#define RING_USH 12288

typedef unsigned short ushort_t;
typedef __attribute__((ext_vector_type(4))) float f32x4;
typedef __attribute__((ext_vector_type(8))) short bf16x8;

__device__ __forceinline__ ushort_t f2bf(float f) {
  union { float f; uint32_t u; } x; x.f = f;
  uint32_t u = x.u;
  uint32_t r = (u + 0x7FFFu + ((u >> 16) & 1u)) >> 16;
  return (ushort_t)r;
}

#define GLOAD16(gsrc, ldst) \
  __builtin_amdgcn_global_load_lds((const __attribute__((address_space(1))) unsigned int*)(gsrc), \
                                   (__attribute__((address_space(3))) unsigned int*)(ldst), 16, 0, 0)

// ---------------- sim reduction: nn[t] = sum_c e^2, dl[t] = sum_c e[t]*e[t-1] ---------
__global__ void sim_reduce_kernel(const float* __restrict__ emb,
                                  float* __restrict__ nn_out,
                                  float* __restrict__ dl_out) {
  const int b = blockIdx.y;
  const int t0 = (blockIdx.x * 64 + threadIdx.x) * 4;
  const int cty = threadIdx.y;
  float nn0=0.f,nn1=0.f,nn2=0.f,nn3=0.f;
  float dl0=0.f,dl1=0.f,dl2=0.f,dl3=0.f;
  const float* base = emb + (size_t)b * C_ * T_;
  for (int c = cty * 128; c < cty * 128 + 128; ++c) {
    const float* row = base + (size_t)c * T_;
    float4 v = *(const float4*)(row + t0);
    float el = (t0 > 0) ? row[t0 - 1] : 0.f;
    nn0 += v.x*v.x; nn1 += v.y*v.y; nn2 += v.z*v.z; nn3 += v.w*v.w;
    dl0 += v.x*el;  dl1 += v.y*v.x; dl2 += v.z*v.y; dl3 += v.w*v.z;
  }
  __shared__ float red[4][64*8];
  float* myr = &red[cty][threadIdx.x * 8];
  if (cty != 0) {
    myr[0]=nn0; myr[1]=nn1; myr[2]=nn2; myr[3]=nn3;
    myr[4]=dl0; myr[5]=dl1; myr[6]=dl2; myr[7]=dl3;
  }
  __syncthreads();
  if (cty == 0) {
    for (int q = 1; q < 4; ++q) {
      float* r = &red[q][threadIdx.x * 8];
      nn0+=r[0]; nn1+=r[1]; nn2+=r[2]; nn3+=r[3];
      dl0+=r[4]; dl1+=r[5]; dl2+=r[6]; dl3+=r[7];
    }
    float* nb = nn_out + (size_t)b * T_ + t0;
    float* db = dl_out + (size_t)b * T_ + t0;
    nb[0]=nn0; nb[1]=nn1; nb[2]=nn2; nb[3]=nn3;
    db[0]=dl0; db[1]=dl1; db[2]=dl2; db[3]=dl3;
  }
}

// ---------------- fused: sim finalize (blocks 0..127) + weight permute (rest) --------
__global__ void prep_small_kernel(const float* __restrict__ nn,
                                  const float* __restrict__ dl,
                                  float* __restrict__ sim,
                                  const float* __restrict__ w,
                                  ushort_t* __restrict__ wbf) {
  const int bid = blockIdx.x;
  if (bid < 128) {
    const int idx = bid * 256 + threadIdx.x;
    const int b = idx >> 12;
    const int t = idx & (T_ - 1);
    const float* nnb = nn + (size_t)b * T_;
    const float* dlb = dl + (size_t)b * T_;
    float nncur = nnb[t];
    float ncur = fmaxf(sqrtf(nncur), EPS_);
    float sc = nncur / (ncur * ncur);
    float sl = 0.f, sr = 0.f;
    if (t > 0) {
      float np = fmaxf(sqrtf(nnb[t - 1]), EPS_);
      sl = dlb[t] / (ncur * np);
    }
    if (t < T_ - 1) {
      float nx = fmaxf(sqrtf(nnb[t + 1]), EPS_);
      sr = dlb[t + 1] / (ncur * nx);
    }
    float* simb = sim + (size_t)b * 3 * T_;
    simb[t] = sl;
    simb[T_ + t] = sc;
    simb[2 * T_ + t] = sr;
  } else {
    const int idx = (bid - 128) * 256 + threadIdx.x;
    if (idx >= O_ * KP_) return;
    const int o = idx / KP_;
    const int p = idx - o * KP_;
    const int g = p / 576; const int r = p - g * 576;
    const int k = r / 192; const int j = r - k * 192;
    const int c_lo = (512 * g - k + 2) / 3;
    const int c_hi = (512 * g + 511 - k) / 3;
    const int c = (c_lo & ~7) + j;
    float v = (c >= c_lo && c <= c_hi) ? w[((size_t)o * C_ + c) * 3 + k] : 0.f;
    wbf[idx] = f2bf(v);
  }
}

// ---------------- feature transpose+convert (+ zero pad rows when x==64) -------------
__global__ void transpose_kernel(const float* __restrict__ feat, ushort_t* __restrict__ Ftp) {
  const int b = blockIdx.z;
  const int c0 = blockIdx.y * 64;
  const int tid = threadIdx.x;
  if (blockIdx.x == T_ / 64) {  // pad rows t=-1 (row 0) and t=T (row 4097)
    if (tid < 64)        Ftp[((size_t)b * FTP_ROWS + 0) * 512 + c0 + tid] = 0;
    else if (tid < 128)  Ftp[((size_t)b * FTP_ROWS + T_ + 1) * 512 + c0 + (tid - 64)] = 0;
    return;
  }
  const int t0 = blockIdx.x * 64;
  __shared__ ushort_t LT[64 * 72];
  {
    const int cl = tid >> 2;
    const int tq = (tid & 3) * 16;
    const float* src = feat + ((size_t)b * C_ + c0 + cl) * T_ + t0 + tq;
    for (int q = 0; q < 4; ++q) {
      float4 v = *(const float4*)(src + q * 4);
      const int t = tq + q * 4;
      LT[(t + 0) * 72 + cl] = f2bf(v.x);
      LT[(t + 1) * 72 + cl] = f2bf(v.y);
      LT[(t + 2) * 72 + cl] = f2bf(v.z);
      LT[(t + 3) * 72 + cl] = f2bf(v.w);
    }
  }
  __syncthreads();
  {
    const int tl = tid >> 2;
    const int cq = (tid & 3) * 16;
    ushort_t* dst = Ftp + ((size_t)b * FTP_ROWS + t0 + tl + 1) * 512 + c0 + cq;
    *(uint4*)(dst) = *(const uint4*)&LT[tl * 72 + cq];
    *(uint4*)(dst + 8) = *(const uint4*)&LT[tl * 72 + cq + 8];
  }
}

// ------ main GEMM: 256x128, 4-ring half-slabs, FRAGMENT PREFETCH + counted vmcnt -----
// Phase u: STAGE(u+3) | ds_read frags(u+1)->buf[(u+1)&1] | MFMA(u) on buf[u&1]
//          | lgkmcnt(0) | vmcnt(3) [stage(u+2) landed] | barrier
__global__ __launch_bounds__(512, 2)
void conv_gemm_kernel(const ushort_t* __restrict__ Ftp,
                      const ushort_t* __restrict__ wbf,
                      const float* __restrict__ sim,
                      float* __restrict__ out) {
  __shared__ __align__(16) ushort_t lds[4 * RING_USH];  // 96 KB

  const int b = blockIdx.z;
  const int oBase = blockIdx.y * BM;
  const int tBase = blockIdx.x * BN;

  const int tid = threadIdx.x;
  const int lane = tid & 63;
  const int wid = tid >> 6;           // 8 waves
  const int wm = wid >> 1;            // 0..3 (o)
  const int wn = wid & 1;             // 0..1 (t)
  const int llo = lane & 15, lhi = lane >> 4;

  // ds_read chunk swizzle (2-way banks = free) + matching staging source swizzle
  const int rdsw = ((lhi ^ ((llo >> 1) & 3)) << 3);
  const int gch = ((lane & 3) ^ ((lane >> 3) & 3)) << 3;
  const int arow = wid * 32 + (lane >> 2);   // A rows (second instr adds 16)
  const int brow = wid * 16 + (lane >> 2);   // B rows

  const ushort_t* ftpB = Ftp + (size_t)b * FTP_ROWS * 512;
  const float* simB = sim + (size_t)b * 3 * T_;

  // ---- preload sim, pin, drain (keeps vmcnt counting exact) ----
  float sv[3][4];
#pragma unroll
  for (int g = 0; g < 3; ++g)
#pragma unroll
    for (int n = 0; n < 4; ++n) {
      sv[g][n] = simB[g * T_ + tBase + wn * 64 + n * 16 + llo];
      asm volatile("" : "+v"(sv[g][n]));
    }
  asm volatile("s_waitcnt vmcnt(0)" ::: "memory");

  f32x4 cacc[4][4], oacc[4][4];
  const f32x4 vzero = {0.f, 0.f, 0.f, 0.f};
#pragma unroll
  for (int m = 0; m < 4; ++m)
#pragma unroll
    for (int n = 0; n < 4; ++n) { cacc[m][n] = vzero; oacc[m][n] = vzero; }

  // ---- stage half-slab u into ring[u&3]: 2 A-loads + 1 B-load per thread ----
  auto STAGE = [&](int u) {
    const int s2 = u >> 1, h = u & 1;
    const int g = s2 / 9, r = s2 - g * 9, k = r / 3, jb = r - k * 3;
    const int c_st = ((512 * g - k + 2) / 3) & ~7;
    ushort_t* ring = lds + (u & 3) * RING_USH;
    const ushort_t* aS = wbf + (size_t)(oBase + arow) * KP_ + s2 * 64 + h * 32 + gch;
    GLOAD16(aS, ring + wid * 1024);
    GLOAD16(aS + (size_t)16 * KP_, ring + wid * 1024 + 512);
    const ushort_t* bS = ftpB + (size_t)(tBase + brow + k) * 512 + c_st + jb * 64 + h * 32 + gch;
    GLOAD16(bS, ring + 8192 + wid * 512);
  };

  bf16x8 afb[2][4], bfb[2][4];   // fragment double-buffer (static idx via full unroll)

  // ---- prologue: 3 half-slabs in flight; stage(0),(1) landed; read frags(0) ----
  STAGE(0); STAGE(1); STAGE(2);
  __builtin_amdgcn_sched_barrier(0);
  asm volatile("s_waitcnt vmcnt(3)" ::: "memory");   // stage(0),(1) landed; stage(2) in flight
  __builtin_amdgcn_sched_barrier(0);
  __builtin_amdgcn_s_barrier();
  __builtin_amdgcn_sched_barrier(0);
  {
    const ushort_t* Ah = lds;            // slot 0
    const ushort_t* Bh = Ah + 8192;
#pragma unroll
    for (int m = 0; m < 4; ++m)
      afb[0][m] = *(const bf16x8*)&Ah[(wm * 64 + m * 16 + llo) * 32 + rdsw];
#pragma unroll
    for (int n = 0; n < 4; ++n)
      bfb[0][n] = *(const bf16x8*)&Bh[(wn * 64 + n * 16 + llo) * 32 + rdsw];
  }
  __builtin_amdgcn_sched_barrier(0);

#pragma unroll
  for (int u = 0; u < 54; ++u) {
    // stage u+3 into slot (u-1)&3 (readers drained end of phase u-2, 2 barriers ago)
    if (u + 3 < 54) STAGE(u + 3);
    __builtin_amdgcn_sched_barrier(0);

    // prefetch next phase's fragments (slot (u+1)&3; all waves' stage(u+1) landed
    // because everyone waited vmcnt for it before the barrier we just crossed)
    if (u + 1 < 54) {
      const ushort_t* Ah = lds + ((u + 1) & 3) * RING_USH;
      const ushort_t* Bh = Ah + 8192;
#pragma unroll
      for (int m = 0; m < 4; ++m)
        afb[(u + 1) & 1][m] = *(const bf16x8*)&Ah[(wm * 64 + m * 16 + llo) * 32 + rdsw];
#pragma unroll
      for (int n = 0; n < 4; ++n)
        bfb[(u + 1) & 1][n] = *(const bf16x8*)&Bh[(wn * 64 + n * 16 + llo) * 32 + rdsw];
    }
    __builtin_amdgcn_sched_barrier(0);

    // MFMA on fragments read LAST phase (ds latency hidden under this cluster)
    __builtin_amdgcn_s_setprio(1);
#pragma unroll
    for (int m = 0; m < 4; ++m)
#pragma unroll
      for (int n = 0; n < 4; ++n)
        cacc[m][n] = __builtin_amdgcn_mfma_f32_16x16x32_bf16(afb[u & 1][m], bfb[u & 1][n], cacc[m][n], 0, 0, 0);
    __builtin_amdgcn_s_setprio(0);

    // group boundary: fold sim_g * partial into output accumulator
    if (u == 17 || u == 35 || u == 53) {
      const int g = u / 18;
#pragma unroll
      for (int n = 0; n < 4; ++n) {
        const float sc = sv[g][n];
#pragma unroll
        for (int m = 0; m < 4; ++m) {
          oacc[m][n] += sc * cacc[m][n];
          cacc[m][n] = vzero;
        }
      }
    }

    asm volatile("s_waitcnt lgkmcnt(0)" ::: "memory");  // my ds_reads retired (WAR guard)
    __builtin_amdgcn_sched_barrier(0);
    // counted wait: stage(u+2) landed (next phase reads frags(u+2)); stage(u+3) in flight
    if (u <= 50)      { asm volatile("s_waitcnt vmcnt(3)" ::: "memory"); }
    else if (u == 51) { asm volatile("s_waitcnt vmcnt(0)" ::: "memory"); }
    __builtin_amdgcn_sched_barrier(0);
    __builtin_amdgcn_s_barrier();
    __builtin_amdgcn_sched_barrier(0);
  }

  // ---- epilogue: D layout col=lane&15, row=(lane>>4)*4+reg ----
  float* outB = out + ((size_t)b * O_ + oBase) * T_ + tBase;
#pragma unroll
  for (int m = 0; m < 4; ++m) {
    const int r0 = wm * 64 + m * 16 + lhi * 4;
#pragma unroll
    for (int n = 0; n < 4; ++n) {
      const int cg = wn * 64 + n * 16 + llo;
#pragma unroll
      for (int r = 0; r < 4; ++r)
        outB[(size_t)(r0 + r) * T_ + cg] = oacc[m][n][r];
    }
  }
}

extern "C" void kernel_launch(void* const* d_in, const int* in_sizes, int n_in,
                              void* d_out, int out_size, void* d_ws, size_t ws_size,
                              hipStream_t stream) {
  const float* feature   = (const float*)d_in[0];
  const float* embedding = (const float*)d_in[1];
  const float* weight    = (const float*)d_in[2];
  float* out = (float*)d_out;

  float* ws  = (float*)d_ws;
  float* nn  = ws;                                   // B*T f32
  float* dl  = nn + (size_t)B_ * T_;                 // B*T f32
  float* sim = dl + (size_t)B_ * T_;                 // B*3*T f32
  ushort_t* wbf = (ushort_t*)(sim + (size_t)3 * B_ * T_);   // O*KP bf16
  ushort_t* Ftp = wbf + (size_t)O_ * KP_;                   // B*FTP_ROWS*C bf16

  sim_reduce_kernel<<<dim3(T_ / 256, B_), dim3(64, 4), 0, stream>>>(embedding, nn, dl);
  prep_small_kernel<<<dim3(128 + (O_ * KP_ + 255) / 256), 256, 0, stream>>>(nn, dl, sim, weight, wbf);
  transpose_kernel<<<dim3(T_ / 64 + 1, C_ / 64, B_), 256, 0, stream>>>(feature, Ftp);
  conv_gemm_kernel<<<dim3(T_ / BN, O_ / BM, B_), 512, 0, stream>>>(Ftp, wbf, sim, out);
}

// Round 9
// 112.672 us; speedup vs baseline: 1.5783x; 1.0465x over previous
//
#include <hip/hip_runtime.h>
#include <hip/hip_bf16.h>
#include <stdint.h>

#define B_ 8
#define C_ 512
#define T_ 4096
#define O_ 512
#define KP_ 1728   /* padded K: 3 groups x 3 k x 192 */
#define EPS_ 1e-8f

#define BM 256
#define BN 256
#define FTP_ROWS 4104

/* LDS ring: 4 half-slab slots, each [A 256x32 = 8192 ush][B 256x32 = 8192 ush] */
#define SLOT_USH 16384
#define LDS_BYTES (4 * SLOT_USH * 2)  /* 131072 */

typedef unsigned short ushort_t;
typedef __attribute__((ext_vector_type(4))) float f32x4;
typedef __attribute__((ext_vector_type(8))) short bf16x8;

__device__ __forceinline__ ushort_t f2bf(float f) {
  union { float f; uint32_t u; } x; x.f = f;
  uint32_t u = x.u;
  uint32_t r = (u + 0x7FFFu + ((u >> 16) & 1u)) >> 16;
  return (ushort_t)r;
}

#define GLOAD16(gsrc, ldst) \
  __builtin_amdgcn_global_load_lds((const __attribute__((address_space(1))) unsigned int*)(gsrc), \
                                   (__attribute__((address_space(3))) unsigned int*)(ldst), 16, 0, 0)

// ---------------- sim reduction: nn[t] = sum_c e^2, dl[t] = sum_c e[t]*e[t-1] ---------
__global__ void sim_reduce_kernel(const float* __restrict__ emb,
                                  float* __restrict__ nn_out,
                                  float* __restrict__ dl_out) {
  const int b = blockIdx.y;
  const int t0 = (blockIdx.x * 64 + threadIdx.x) * 4;
  const int cty = threadIdx.y;
  float nn0=0.f,nn1=0.f,nn2=0.f,nn3=0.f;
  float dl0=0.f,dl1=0.f,dl2=0.f,dl3=0.f;
  const float* base = emb + (size_t)b * C_ * T_;
  for (int c = cty * 128; c < cty * 128 + 128; ++c) {
    const float* row = base + (size_t)c * T_;
    float4 v = *(const float4*)(row + t0);
    float el = (t0 > 0) ? row[t0 - 1] : 0.f;
    nn0 += v.x*v.x; nn1 += v.y*v.y; nn2 += v.z*v.z; nn3 += v.w*v.w;
    dl0 += v.x*el;  dl1 += v.y*v.x; dl2 += v.z*v.y; dl3 += v.w*v.z;
  }
  __shared__ float red[4][64*8];
  float* myr = &red[cty][threadIdx.x * 8];
  if (cty != 0) {
    myr[0]=nn0; myr[1]=nn1; myr[2]=nn2; myr[3]=nn3;
    myr[4]=dl0; myr[5]=dl1; myr[6]=dl2; myr[7]=dl3;
  }
  __syncthreads();
  if (cty == 0) {
    for (int q = 1; q < 4; ++q) {
      float* r = &red[q][threadIdx.x * 8];
      nn0+=r[0]; nn1+=r[1]; nn2+=r[2]; nn3+=r[3];
      dl0+=r[4]; dl1+=r[5]; dl2+=r[6]; dl3+=r[7];
    }
    float* nb = nn_out + (size_t)b * T_ + t0;
    float* db = dl_out + (size_t)b * T_ + t0;
    nb[0]=nn0; nb[1]=nn1; nb[2]=nn2; nb[3]=nn3;
    db[0]=dl0; db[1]=dl1; db[2]=dl2; db[3]=dl3;
  }
}

// ---------------- fused: sim finalize (blocks 0..127) + weight permute (rest) --------
__global__ void prep_small_kernel(const float* __restrict__ nn,
                                  const float* __restrict__ dl,
                                  float* __restrict__ sim,
                                  const float* __restrict__ w,
                                  ushort_t* __restrict__ wbf) {
  const int bid = blockIdx.x;
  if (bid < 128) {
    const int idx = bid * 256 + threadIdx.x;
    const int b = idx >> 12;
    const int t = idx & (T_ - 1);
    const float* nnb = nn + (size_t)b * T_;
    const float* dlb = dl + (size_t)b * T_;
    float nncur = nnb[t];
    float ncur = fmaxf(sqrtf(nncur), EPS_);
    float sc = nncur / (ncur * ncur);
    float sl = 0.f, sr = 0.f;
    if (t > 0) {
      float np = fmaxf(sqrtf(nnb[t - 1]), EPS_);
      sl = dlb[t] / (ncur * np);
    }
    if (t < T_ - 1) {
      float nx = fmaxf(sqrtf(nnb[t + 1]), EPS_);
      sr = dlb[t + 1] / (ncur * nx);
    }
    float* simb = sim + (size_t)b * 3 * T_;
    simb[t] = sl;
    simb[T_ + t] = sc;
    simb[2 * T_ + t] = sr;
  } else {
    const int idx = (bid - 128) * 256 + threadIdx.x;
    if (idx >= O_ * KP_) return;
    const int o = idx / KP_;
    const int p = idx - o * KP_;
    const int g = p / 576; const int r = p - g * 576;
    const int k = r / 192; const int j = r - k * 192;
    const int c_lo = (512 * g - k + 2) / 3;
    const int c_hi = (512 * g + 511 - k) / 3;
    const int c = (c_lo & ~7) + j;
    float v = (c >= c_lo && c <= c_hi) ? w[((size_t)o * C_ + c) * 3 + k] : 0.f;
    wbf[idx] = f2bf(v);
  }
}

// ---------------- feature transpose+convert (+ zero pad rows when x==64) -------------
__global__ void transpose_kernel(const float* __restrict__ feat, ushort_t* __restrict__ Ftp) {
  const int b = blockIdx.z;
  const int c0 = blockIdx.y * 64;
  const int tid = threadIdx.x;
  if (blockIdx.x == T_ / 64) {  // pad rows t=-1 (row 0) and t=T (row 4097)
    if (tid < 64)        Ftp[((size_t)b * FTP_ROWS + 0) * 512 + c0 + tid] = 0;
    else if (tid < 128)  Ftp[((size_t)b * FTP_ROWS + T_ + 1) * 512 + c0 + (tid - 64)] = 0;
    return;
  }
  const int t0 = blockIdx.x * 64;
  __shared__ ushort_t LT[64 * 72];
  {
    const int cl = tid >> 2;
    const int tq = (tid & 3) * 16;
    const float* src = feat + ((size_t)b * C_ + c0 + cl) * T_ + t0 + tq;
    for (int q = 0; q < 4; ++q) {
      float4 v = *(const float4*)(src + q * 4);
      const int t = tq + q * 4;
      LT[(t + 0) * 72 + cl] = f2bf(v.x);
      LT[(t + 1) * 72 + cl] = f2bf(v.y);
      LT[(t + 2) * 72 + cl] = f2bf(v.z);
      LT[(t + 3) * 72 + cl] = f2bf(v.w);
    }
  }
  __syncthreads();
  {
    const int tl = tid >> 2;
    const int cq = (tid & 3) * 16;
    ushort_t* dst = Ftp + ((size_t)b * FTP_ROWS + t0 + tl + 1) * 512 + c0 + cq;
    *(uint4*)(dst) = *(const uint4*)&LT[tl * 72 + cq];
    *(uint4*)(dst + 8) = *(const uint4*)&LT[tl * 72 + cq + 8];
  }
}

// ---- main GEMM: 256x256 tile, K-32 4-ring, counted vmcnt, single Horner accumulator -
// Group order (l, r, c): O = ((G_l*(s_l/s'_r) + G_r)*(s'_r/s_c) + G_c)*s_c
__device__ __forceinline__ constexpr int slab_of_u(int u) {
  return (u < 18) ? (u >> 1) : ((u < 36) ? (u >> 1) + 9 : (u >> 1) - 9);
}

__global__ __launch_bounds__(512, 2)
void conv_gemm_kernel(const ushort_t* __restrict__ Ftp,
                      const ushort_t* __restrict__ wbf,
                      const float* __restrict__ sim,
                      float* __restrict__ out) {
  extern __shared__ ushort_t lds[];   // 4 x 32 KB slots

  const int b = blockIdx.z;
  const int oBase = blockIdx.y * BM;
  const int tBase = blockIdx.x * BN;

  const int tid = threadIdx.x;
  const int lane = tid & 63;
  const int wid = tid >> 6;           // 8 waves
  const int wm = wid >> 2;            // 0..1 (o, 128 rows each)
  const int wn = wid & 3;             // 0..3 (t, 64 cols each)
  const int llo = lane & 15, lhi = lane >> 4;

  // ds_read chunk swizzle (2-way banks = free) + matching staging source swizzle
  const int rdsw = ((lhi ^ ((llo >> 1) & 3)) << 3);
  const int gch = ((lane & 3) ^ ((lane >> 3) & 3)) << 3;
  const int srow = wid * 32 + (lane >> 2);   // staging row (2nd instr adds 16)

  const ushort_t* ftpB = Ftp + (size_t)b * FTP_ROWS * 512;
  const float* simB = sim + (size_t)b * 3 * T_;

  const ushort_t* aSrc = wbf + (size_t)(oBase + srow) * KP_ + gch;
  const ushort_t* bRow = ftpB + (size_t)(tBase + srow) * 512 + gch;

  // ---- sim preload -> Horner ratios, pin, drain (keeps vmcnt counting exact) ----
  float rat0[4], rat1[4], fin[4];
#pragma unroll
  for (int n = 0; n < 4; ++n) {
    const int col = tBase + wn * 64 + n * 16 + llo;
    float s_l = simB[col];
    float s_c = simB[T_ + col];
    float s_r = simB[2 * T_ + col];
    float shr = (fabsf(s_r) < 1e-6f) ? copysignf(1e-6f, s_r) : s_r;
    float shc = fmaxf(s_c, 1e-6f);
    rat0[n] = s_l / shr;
    rat1[n] = shr / shc;
    fin[n]  = s_c;
    asm volatile("" : "+v"(rat0[n]), "+v"(rat1[n]), "+v"(fin[n]));
  }
  asm volatile("s_waitcnt vmcnt(0)" ::: "memory");

  f32x4 cacc[8][4];
  const f32x4 vzero = {0.f, 0.f, 0.f, 0.f};
#pragma unroll
  for (int m = 0; m < 8; ++m)
#pragma unroll
    for (int n = 0; n < 4; ++n) cacc[m][n] = vzero;

  // ---- stage half-slab u into slot u&3: 2 A-gloads + 2 B-gloads per thread ----
  auto STAGE = [&](int u) {
    const int s2 = slab_of_u(u), h = u & 1;
    const int g = s2 / 9, r = s2 - g * 9, k = r / 3, jb = r - k * 3;
    const int c_st = ((512 * g - k + 2) / 3) & ~7;
    ushort_t* slot = lds + (u & 3) * SLOT_USH;
    const ushort_t* aS = aSrc + s2 * 64 + h * 32;
    GLOAD16(aS, slot + wid * 1024);
    GLOAD16(aS + (size_t)16 * KP_, slot + wid * 1024 + 512);
    const ushort_t* bS = bRow + k * 512 + c_st + jb * 64 + h * 32;
    GLOAD16(bS, slot + 8192 + wid * 1024);
    GLOAD16(bS + (size_t)16 * 512, slot + 8192 + wid * 1024 + 512);
  };

  // ---- prologue: 3 half-slabs in flight (12 loads) ----
  STAGE(0); STAGE(1); STAGE(2);
  __builtin_amdgcn_sched_barrier(0);

#pragma unroll
  for (int u = 0; u < 54; ++u) {
    // counted wait: stage(u) landed; up to 2 newer stages (8 loads) stay in flight
    if (u <= 51)      { asm volatile("s_waitcnt vmcnt(8)" ::: "memory"); }
    else if (u == 52) { asm volatile("s_waitcnt vmcnt(4)" ::: "memory"); }
    else              { asm volatile("s_waitcnt vmcnt(0)" ::: "memory"); }
    __builtin_amdgcn_sched_barrier(0);
    __builtin_amdgcn_s_barrier();   // all waves: stage(u) landed; slot (u+3)&3 drained
    __builtin_amdgcn_sched_barrier(0);

    if (u + 3 < 54) STAGE(u + 3);   // writes slot (u-1)&3, read-drained 2 barriers ago
    __builtin_amdgcn_sched_barrier(0);

    const ushort_t* Ah = lds + (u & 3) * SLOT_USH;
    const ushort_t* Bh = Ah + 8192;
    bf16x8 af[8], bfv[4];
#pragma unroll
    for (int m = 0; m < 8; ++m)
      af[m] = *(const bf16x8*)&Ah[(wm * 128 + m * 16 + llo) * 32 + rdsw];
#pragma unroll
    for (int n = 0; n < 4; ++n)
      bfv[n] = *(const bf16x8*)&Bh[(wn * 64 + n * 16 + llo) * 32 + rdsw];

    __builtin_amdgcn_s_setprio(1);
#pragma unroll
    for (int m = 0; m < 8; ++m)
#pragma unroll
      for (int n = 0; n < 4; ++n)
        cacc[m][n] = __builtin_amdgcn_mfma_f32_16x16x32_bf16(af[m], bfv[n], cacc[m][n], 0, 0, 0);
    __builtin_amdgcn_s_setprio(0);

    // Horner group boundaries: rescale the single accumulator
    if (u == 17 || u == 35 || u == 53) {
#pragma unroll
      for (int n = 0; n < 4; ++n) {
        const float sc = (u == 17) ? rat0[n] : (u == 35) ? rat1[n] : fin[n];
#pragma unroll
        for (int m = 0; m < 8; ++m) cacc[m][n] *= sc;
      }
    }

    asm volatile("s_waitcnt lgkmcnt(0)" ::: "memory");  // my ds_reads retired (WAR guard)
    __builtin_amdgcn_sched_barrier(0);
  }

  // ---- epilogue: D layout col=lane&15, row=(lane>>4)*4+reg ----
  float* outB = out + ((size_t)b * O_ + oBase) * T_ + tBase;
#pragma unroll
  for (int m = 0; m < 8; ++m) {
    const int r0 = wm * 128 + m * 16 + lhi * 4;
#pragma unroll
    for (int n = 0; n < 4; ++n) {
      const int cg = wn * 64 + n * 16 + llo;
#pragma unroll
      for (int r = 0; r < 4; ++r)
        outB[(size_t)(r0 + r) * T_ + cg] = cacc[m][n][r];
    }
  }
}

extern "C" void kernel_launch(void* const* d_in, const int* in_sizes, int n_in,
                              void* d_out, int out_size, void* d_ws, size_t ws_size,
                              hipStream_t stream) {
  const float* feature   = (const float*)d_in[0];
  const float* embedding = (const float*)d_in[1];
  const float* weight    = (const float*)d_in[2];
  float* out = (float*)d_out;

  float* ws  = (float*)d_ws;
  float* nn  = ws;                                   // B*T f32
  float* dl  = nn + (size_t)B_ * T_;                 // B*T f32
  float* sim = dl + (size_t)B_ * T_;                 // B*3*T f32
  ushort_t* wbf = (ushort_t*)(sim + (size_t)3 * B_ * T_);   // O*KP bf16
  ushort_t* Ftp = wbf + (size_t)O_ * KP_;                   // B*FTP_ROWS*C bf16

  (void)hipFuncSetAttribute((const void*)conv_gemm_kernel,
                            hipFuncAttributeMaxDynamicSharedMemorySize, LDS_BYTES);

  sim_reduce_kernel<<<dim3(T_ / 256, B_), dim3(64, 4), 0, stream>>>(embedding, nn, dl);
  prep_small_kernel<<<dim3(128 + (O_ * KP_ + 255) / 256), 256, 0, stream>>>(nn, dl, sim, weight, wbf);
  transpose_kernel<<<dim3(T_ / 64 + 1, C_ / 64, B_), 256, 0, stream>>>(feature, Ftp);
  conv_gemm_kernel<<<dim3(T_ / BN, O_ / BM, B_), 512, LDS_BYTES, stream>>>(Ftp, wbf, sim, out);
}